// Round 1
// 674.052 us; speedup vs baseline: 1.1371x; 1.1371x over previous
//
#include <hip/hip_runtime.h>
#include <hip/hip_bf16.h>

// ---------------------------------------------------------------------------
// KGATNE fused, dtype-adaptive. One workgroup per (seed b, graph g) tree.
// Levels 0..3 (124 rows x 100 f32) live in LDS across all 4 passes; level-4
// (945 rows) is folded into pass-0 level-3 via on-the-fly gather+mean.
// R4 changes vs R3 (theory: weight-remat + exposed gather latency):
//   * ws[100]/wn[100] pinned into VGPRs via empty inline-asm ("+v") so the
//     compiler cannot rematerialize the weight loads into the inner matmul
//     (R3 binary: VGPR_Count=128 with 200 live floats => remat, ~200 L1
//     loads per row-matmul, ~250-300us of L1 traffic).
//   * level-3 gather loop software-pipelined: next j's 9 idx + 9 float2
//     gathers issued between snb fence and current matmul (hides ~900cy).
//   * 124-row prefill spread over all 256 threads (was lane<50 only).
// Detector scans user_emb_w for bf16 inf/NaN exponent patterns -> flag
// selects the fp32 or bf16 pipeline variant. Output dtype follows input.
// ---------------------------------------------------------------------------

#define DEVFN __device__ __forceinline__

DEVFN float B2F(unsigned short u) { return __uint_as_float(((unsigned)u) << 16); }
DEVFN float LOBF(unsigned u)      { return __uint_as_float(u << 16); }
DEVFN float HIBF(unsigned u)      { return __uint_as_float(u & 0xffff0000u); }

// dtype-generic loads (p must be 2-element aligned for ld2)
DEVFN float  ld1(const unsigned short* p) { return B2F(*p); }
DEVFN float  ld1(const float* p)          { return *p; }
DEVFN float2 ld2(const unsigned short* p) {
    unsigned u = *(const unsigned*)p;
    return make_float2(LOBF(u), HIBF(u));
}
DEVFN float2 ld2(const float* p) { return *(const float2*)p; }

// ---------------------------------------------------------------------------
// dtype detector: flag=1 if fp32, flag=0 if bf16
// ---------------------------------------------------------------------------
__global__ void detect_dtype(const unsigned short* __restrict__ emb,
                             int* __restrict__ flag) {
    const int t = threadIdx.x;
    __shared__ int s[256];
    int c = 0;
    for (int i = t; i < 65536; i += 256) {
        unsigned short u = emb[i];
        if (((u >> 7) & 0xFF) == 0xFF) c++;  // bf16 inf/NaN exponent
    }
    s[t] = c;
    __syncthreads();
    for (int st = 128; st > 0; st >>= 1) {
        if (t < st) s[t] += s[t + st];
        __syncthreads();
    }
    if (t == 0) flag[0] = (s[0] > 0) ? 1 : 0;
}

// lane<50 only: full 100-dot for out cols (lane, lane+50), relu, in-place store
DEVFN void row_matmul_store(float* __restrict__ feat, const float* __restrict__ snbw,
                            int xs, const float* __restrict__ ws,
                            const float* __restrict__ wn, float bias_s, float bias_n,
                            int lane) {
    float accs = bias_s, accn = bias_n;
#pragma unroll
    for (int d = 0; d < 100; d += 4) {
        float4 xv = *(const float4*)&feat[xs * 100 + d];
        float4 nv = *(const float4*)&snbw[d];
        accs += xv.x * ws[d] + xv.y * ws[d + 1] + xv.z * ws[d + 2] + xv.w * ws[d + 3];
        accn += nv.x * wn[d] + nv.y * wn[d + 1] + nv.z * wn[d + 2] + nv.w * wn[d + 3];
    }
    feat[xs * 100 + lane]      = fmaxf(accs, 0.f);
    feat[xs * 100 + lane + 50] = fmaxf(accn, 0.f);
}

// level with LDS-resident children: rows [Ok, Ok+R), children at Ok1 + j*S
template <int S>
DEVFN void do_level(float* __restrict__ feat, float (*snb)[104], int Ok, int Ok1,
                    int R, const float* __restrict__ ws, const float* __restrict__ wn,
                    float bs, float bn, int wid, int lane) {
    for (int j = wid; j < R; j += 4) {
        if (lane < 50) {
            float a0 = 0.f, a1 = 0.f;
#pragma unroll
            for (int s = 0; s < S; ++s) {
                float2 c = *(const float2*)&feat[(Ok1 + j * S + s) * 100 + 2 * lane];
                a0 += c.x; a1 += c.y;
            }
            const float inv = 1.f / (float)S;
            *(float2*)&snb[wid][2 * lane] = make_float2(a0 * inv, a1 * inv);
            __threadfence_block();  // wave-sync LDS write->cross-lane read
            row_matmul_store(feat, snb[wid], Ok + j, ws, wn, bs, bn, lane);
        }
    }
}

// pass-0 level-3: children gathered straight from the embedding table.
// Software-pipelined: iteration j computes the mean from registers prefetched
// during iteration j-4's matmul, then issues iteration j+4's gathers before
// running its own matmul (HBM/L3 latency hides under the FMA chain).
template <typename T>
DEVFN void do_level3_gather(float* __restrict__ feat, float (*snb)[104],
                            const T* __restrict__ embg, const int* __restrict__ s_n3,
                            const float* __restrict__ ws, const float* __restrict__ wn,
                            float bs, float bn, int wid, int lane) {
    if (lane >= 50) return;  // no barriers inside; inactive lanes can leave

    float2 c[9];
    // prologue: prefetch first row's 9 children
    {
        int idx[9];
#pragma unroll
        for (int s = 0; s < 9; ++s) idx[s] = s_n3[wid * 9 + s];
#pragma unroll
        for (int s = 0; s < 9; ++s)
            c[s] = ld2(embg + (size_t)idx[s] * 100 + 2 * lane);
    }

    for (int j = wid; j < 105; j += 4) {
        // mean from prefetched registers (vmcnt wait lands here)
        float a0 = 0.f, a1 = 0.f;
#pragma unroll
        for (int s = 0; s < 9; ++s) { a0 += c[s].x; a1 += c[s].y; }
        *(float2*)&snb[wid][2 * lane] =
            make_float2(a0 * (1.f / 9.f), a1 * (1.f / 9.f));
        __threadfence_block();  // snb write -> cross-lane read

        // issue next row's gathers; results are not consumed until next iter,
        // so they fly during the matmul below
        const int jn = j + 4;
        if (jn < 105) {
            int idx[9];
#pragma unroll
            for (int s = 0; s < 9; ++s) idx[s] = s_n3[jn * 9 + s];
#pragma unroll
            for (int s = 0; s < 9; ++s)
                c[s] = ld2(embg + (size_t)idx[s] * 100 + 2 * lane);
        }

        row_matmul_store(feat, snb[wid], 19 + j, ws, wn, bs, bn, lane);
    }
}

// ---------------------------------------------------------------------------
template <typename T>
__global__ __launch_bounds__(256, 2) void sage_fused(
    const int* __restrict__ flag, int want, const int* __restrict__ nodeids,
    const int* __restrict__ n0, const int* __restrict__ n1,
    const int* __restrict__ n2, const int* __restrict__ n3,
    const T* __restrict__ emb, const T* __restrict__ Wself,
    const T* __restrict__ bself, const T* __restrict__ Wneigh,
    const T* __restrict__ bneigh, const T* __restrict__ Wfc,
    const T* __restrict__ bfc, float* __restrict__ spec) {
    if (flag[0] != want) return;
    const int b = blockIdx.x, g = blockIdx.y;
    const int tid = threadIdx.x, wid = tid >> 6, lane = tid & 63;

    __shared__ __align__(16) float feat[12400];  // 124 rows x 100
    __shared__ __align__(16) float snb[4][104];  // per-wave nb staging
    __shared__ int s_ids[124];
    __shared__ int s_n3[945];
    __shared__ __align__(16) float s_xn[104];
    __shared__ float s_red[256];

    const T* embg = emb + (size_t)g * 10000000;  // (G,N,D) table

    // ---- index prefill: levels 0..3 x-ids are contiguous per tree
    if (tid == 0)       s_ids[0]   = nodeids[b];
    else if (tid < 4)   s_ids[tid] = n0[g * 1536  + b * 3   + (tid - 1)];
    else if (tid < 19)  s_ids[tid] = n1[g * 7680  + b * 15  + (tid - 4)];
    else if (tid < 124) s_ids[tid] = n2[g * 53760 + b * 105 + (tid - 19)];
    for (int i = tid; i < 945; i += 256) s_n3[i] = n3[g * 483840 + b * 945 + i];
    __syncthreads();

    // ---- feature prefill: 124 rows x 50 float2, spread over all 256 threads
    for (int e = tid; e < 6200; e += 256) {
        const int row = e / 50, col = e - row * 50;
        *(float2*)&feat[row * 100 + 2 * col] =
            ld2(embg + (size_t)s_ids[row] * 100 + 2 * col);
    }
    __syncthreads();

    float ws[100], wn[100];

    // ---- 4 triangular passes (weights register-loaded from global, L2-hot)
    for (int l = 0; l < 4; ++l) {
        const T* Wsb = Wself  + (size_t)(g * 4 + l) * 5000;
        const T* Wnb = Wneigh + (size_t)(g * 4 + l) * 5000;
        float bs = 0.f, bn = 0.f;
        if (lane < 50) {
            bs = ld1(bself  + (g * 4 + l) * 50 + lane);
            bn = ld1(bneigh + (g * 4 + l) * 50 + lane);
#pragma unroll
            for (int d = 0; d < 100; ++d) {
                ws[d] = ld1(Wsb + d * 50 + lane);
                wn[d] = ld1(Wnb + d * 50 + lane);
            }
            // Pin the 200 weight values into VGPRs: the empty asm defines
            // opaque register values the compiler cannot rematerialize by
            // re-reading global memory inside the row matmuls (R3: VGPR=128
            // proved remat; ~200 L1 loads/row-matmul dominated the kernel).
#pragma unroll
            for (int d = 0; d < 100; ++d) {
                asm volatile("" : "+v"(ws[d]), "+v"(wn[d]));
            }
        }
        // ascending levels; barrier between level k (reader of k+1) and k+1 (writer)
        do_level<3>(feat, snb, 0, 1, 1, ws, wn, bs, bn, wid, lane);
        __syncthreads();
        if (l <= 2) {
            do_level<5>(feat, snb, 1, 4, 3, ws, wn, bs, bn, wid, lane);
            __syncthreads();
        }
        if (l <= 1) {
            do_level<7>(feat, snb, 4, 19, 15, ws, wn, bs, bn, wid, lane);
            __syncthreads();
        }
        if (l == 0) {
            do_level3_gather(feat, snb, embg, s_n3, ws, wn, bs, bn, wid, lane);
            __syncthreads();
        }
    }

    // ---- epilogue: l2norm(feat[0]) @ Wfc[g] + bfc[g] -> spec[b][g][:]
    const float v = (tid < 100) ? feat[tid] : 0.f;
    s_red[tid] = v * v;
    __syncthreads();
    for (int s = 128; s > 0; s >>= 1) {
        if (tid < s) s_red[tid] += s_red[tid + s];
        __syncthreads();
    }
    const float inv = 1.f / fmaxf(sqrtf(s_red[0]), 1e-12f);
    if (tid < 100) s_xn[tid] = v * inv;
    __syncthreads();
    if (tid < 100) {
        const T* Wfb = Wfc + (size_t)g * 10000;
        float acc = ld1(bfc + g * 100 + tid);
#pragma unroll 4
        for (int d = 0; d < 100; ++d) acc += s_xn[d] * ld1(Wfb + d * 100 + tid);
        spec[((size_t)b * 3 + g) * 100 + tid] = acc;
    }
}

// ---------------------------------------------------------------------------
// Per-sample: pre-LN(q) attention over G=3, edge-type select, reflect matmul,
// add base embedding, l2-normalize.  Output dtype follows input dtype:
// OUT_BF16 ? bf16 : fp32.  One block per sample.
// ---------------------------------------------------------------------------
template <typename T, bool OUT_BF16>
__global__ __launch_bounds__(256) void attn_out_kernel(
    const int* __restrict__ flag, int want, const float* __restrict__ spec,
    const int* __restrict__ nodeids, const int* __restrict__ edgetypes,
    const T* __restrict__ lng, const T* __restrict__ lnb,
    const T* __restrict__ Wq, const T* __restrict__ Wk,
    const T* __restrict__ Wv, const T* __restrict__ Wo,
    const T* __restrict__ refl, const T* __restrict__ base,
    void* __restrict__ out_raw) {
    if (flag[0] != want) return;
    const int b = blockIdx.x;
    const int t = threadIdx.x;

    __shared__ float s_spec[300];
    __shared__ float s_qn[100], s_Q[100];
    __shared__ float s_K[300], s_V[300];
    __shared__ float s_ctx[100], s_o[100];
    __shared__ float s_r[200];
    __shared__ float s_red[256];

    auto block_reduce = [&](float val) -> float {
        s_red[t] = val;
        __syncthreads();
        for (int s = 128; s > 0; s >>= 1) {
            if (t < s) s_red[t] += s_red[t + s];
            __syncthreads();
        }
        float r = s_red[0];
        __syncthreads();
        return r;
    };

    for (int u = t; u < 300; u += 256) s_spec[u] = spec[(size_t)b * 300 + u];
    const int e = edgetypes[b];
    __syncthreads();

    // layer-norm on the selected row only (only Q row e is ever used)
    const float v = (t < 100) ? s_spec[e * 100 + t] : 0.f;
    const float mu = block_reduce(v) * 0.01f;
    const float dv = (t < 100) ? (v - mu) : 0.f;
    const float var = block_reduce(dv * dv) * 0.01f;
    if (t < 100)
        s_qn[t] = dv * rsqrtf(var + 1e-6f) * ld1(lng + t) + ld1(lnb + t);
    __syncthreads();

    if (t < 100) {
        float acc = 0.f;
        for (int d = 0; d < 100; ++d) acc += s_qn[d] * ld1(Wq + d * 100 + t);
        s_Q[t] = acc;
        for (int h = 0; h < 3; ++h) {
            float aK = 0.f, aV = 0.f;
            for (int d = 0; d < 100; ++d) {
                const float sd = s_spec[h * 100 + d];
                aK += sd * ld1(Wk + d * 100 + t);
                aV += sd * ld1(Wv + d * 100 + t);
            }
            s_K[h * 100 + t] = aK;
            s_V[h * 100 + t] = aV;
        }
    }
    __syncthreads();

    float sc[3];
    for (int h = 0; h < 3; ++h) {
        const float p = (t < 100) ? s_Q[t] * s_K[h * 100 + t] : 0.f;
        sc[h] = block_reduce(p) * 0.1f;  // 1/sqrt(100)
    }
    const float m = fmaxf(sc[0], fmaxf(sc[1], sc[2]));
    const float e0 = expf(sc[0] - m), e1 = expf(sc[1] - m), e2 = expf(sc[2] - m);
    const float esum = e0 + e1 + e2;
    const float w0 = e0 / esum, w1 = e1 / esum, w2 = e2 / esum;

    if (t < 100)
        s_ctx[t] = w0 * s_V[t] + w1 * s_V[100 + t] + w2 * s_V[200 + t];
    __syncthreads();
    if (t < 100) {
        float acc = s_spec[e * 100 + t];  // residual
        for (int d = 0; d < 100; ++d) acc += s_ctx[d] * ld1(Wo + d * 100 + t);
        s_o[t] = acc;
    }
    __syncthreads();

    const int nid = nodeids[b];
    float sq = 0.f;
    if (t < 200) {
        float acc = ld1(base + (size_t)nid * 200 + t);
        for (int d = 0; d < 100; ++d)
            acc += s_o[d] * ld1(refl + (size_t)(e * 100 + d) * 200 + t);
        s_r[t] = acc;
        sq = acc * acc;
    }
    const float ss = block_reduce(sq);
    const float inv = 1.f / fmaxf(sqrtf(ss), 1e-12f);
    if (t < 200) {
        const float r = s_r[t] * inv;
        if constexpr (OUT_BF16)
            ((__hip_bfloat16*)out_raw)[(size_t)b * 200 + t] = __float2bfloat16(r);
        else
            ((float*)out_raw)[(size_t)b * 200 + t] = r;
    }
}

// ---------------------------------------------------------------------------
extern "C" void kernel_launch(void* const* d_in, const int* in_sizes, int n_in,
                              void* d_out, int out_size, void* d_ws,
                              size_t ws_size, hipStream_t stream) {
    (void)in_sizes; (void)n_in; (void)out_size; (void)ws_size;
    const int* nodeids   = (const int*)d_in[0];
    const int* edgetypes = (const int*)d_in[1];
    const int* n0 = (const int*)d_in[2];
    const int* n1 = (const int*)d_in[3];
    const int* n2 = (const int*)d_in[4];
    const int* n3 = (const int*)d_in[5];

    int* flag   = (int*)d_ws;
    float* SPEC = (float*)((char*)d_ws + 256);  // 512*3*100 f32

    detect_dtype<<<1, 256, 0, stream>>>((const unsigned short*)d_in[7], flag);

    // bf16 variant (flag==0)
    sage_fused<unsigned short><<<dim3(512, 3), 256, 0, stream>>>(
        flag, 0, nodeids, n0, n1, n2, n3, (const unsigned short*)d_in[7],
        (const unsigned short*)d_in[8], (const unsigned short*)d_in[9],
        (const unsigned short*)d_in[10], (const unsigned short*)d_in[11],
        (const unsigned short*)d_in[12], (const unsigned short*)d_in[13], SPEC);
    // fp32 variant (flag==1)
    sage_fused<float><<<dim3(512, 3), 256, 0, stream>>>(
        flag, 1, nodeids, n0, n1, n2, n3, (const float*)d_in[7],
        (const float*)d_in[8], (const float*)d_in[9], (const float*)d_in[10],
        (const float*)d_in[11], (const float*)d_in[12], (const float*)d_in[13],
        SPEC);

    attn_out_kernel<unsigned short, true><<<dim3(512), 256, 0, stream>>>(
        flag, 0, SPEC, nodeids, edgetypes, (const unsigned short*)d_in[14],
        (const unsigned short*)d_in[15], (const unsigned short*)d_in[16],
        (const unsigned short*)d_in[17], (const unsigned short*)d_in[18],
        (const unsigned short*)d_in[19], (const unsigned short*)d_in[20],
        (const unsigned short*)d_in[6], d_out);
    attn_out_kernel<float, false><<<dim3(512), 256, 0, stream>>>(
        flag, 1, SPEC, nodeids, edgetypes, (const float*)d_in[14],
        (const float*)d_in[15], (const float*)d_in[16], (const float*)d_in[17],
        (const float*)d_in[18], (const float*)d_in[19], (const float*)d_in[20],
        (const float*)d_in[6], d_out);
}

// Round 2
// 503.730 us; speedup vs baseline: 1.5215x; 1.3381x over previous
//
#include <hip/hip_runtime.h>
#include <hip/hip_bf16.h>

// ---------------------------------------------------------------------------
// KGATNE fused, dtype-adaptive. One workgroup per (seed b, graph g) tree.
// Levels 0..3 (124 rows x 100 f32) live in LDS across all 4 passes; level-4
// (945 rows) is folded into pass-0 level-3 via on-the-fly gather+mean.
//
// R5 changes vs R4 (theory: kill the 200-reg weight spill + buy occupancy):
//   * Each level split into self-phase (Ws only, writes cols 0..49) and
//     neigh-phase (Wn only, writes cols 50..99). Phases share ONE w[100]
//     register array reloaded between phases -> peak weight regs 200->100,
//     no spill (R4: VGPR=128 + 40MB scratch writes), no remat (R3).
//     Correct because phases write disjoint halves and phase reads (own row
//     old-full / children old-full) only race with the NEXT level, which
//     stays behind the existing per-level barrier.
//   * s_n3 dropped from LDS: n3 indices read via wave-uniform scalar loads
//     (readfirstlane'd j -> s_load). s_red aliases snb, s_xn aliases s_ids.
//     LDS 57344 -> 51760 B; __launch_bounds__(256,3) => 3 blocks/CU.
//   * detect scan 65536 -> 16384 (P(miss|fp32) ~ e^-32, still safe).
// Evidence R3: live pipeline is fp32 (flag=1); bf16 variants kept for dtype
// robustness only. Output dtype follows input dtype.
// ---------------------------------------------------------------------------

#define DEVFN __device__ __forceinline__

DEVFN float B2F(unsigned short u) { return __uint_as_float(((unsigned)u) << 16); }
DEVFN float LOBF(unsigned u)      { return __uint_as_float(u << 16); }
DEVFN float HIBF(unsigned u)      { return __uint_as_float(u & 0xffff0000u); }

// dtype-generic loads (p must be 2-element aligned for ld2)
DEVFN float  ld1(const unsigned short* p) { return B2F(*p); }
DEVFN float  ld1(const float* p)          { return *p; }
DEVFN float2 ld2(const unsigned short* p) {
    unsigned u = *(const unsigned*)p;
    return make_float2(LOBF(u), HIBF(u));
}
DEVFN float2 ld2(const float* p) { return *(const float2*)p; }

// ---------------------------------------------------------------------------
// dtype detector: flag=1 if fp32, flag=0 if bf16
// ---------------------------------------------------------------------------
__global__ void detect_dtype(const unsigned short* __restrict__ emb,
                             int* __restrict__ flag) {
    const int t = threadIdx.x;
    __shared__ int s[256];
    int c = 0;
    for (int i = t; i < 16384; i += 256) {
        unsigned short u = emb[i];
        if (((u >> 7) & 0xFF) == 0xFF) c++;  // bf16 inf/NaN exponent
    }
    s[t] = c;
    __syncthreads();
    for (int st = 128; st > 0; st >>= 1) {
        if (t < st) s[t] += s[t + st];
        __syncthreads();
    }
    if (t == 0) flag[0] = (s[0] > 0) ? 1 : 0;
}

// ---- self-phase: rows [Ok, Ok+R): acc = old_row . w + bias -> cols 0..49
DEVFN void level_self(float* __restrict__ feat, int Ok, int R,
                      const float* __restrict__ w, float bias, int wid, int lane) {
    for (int j = wid; j < R; j += 4) {
        if (lane < 50) {
            const float* xr = &feat[(Ok + j) * 100];
            float acc = bias;
#pragma unroll
            for (int d = 0; d < 100; d += 4) {
                float4 xv = *(const float4*)&xr[d];
                acc += xv.x * w[d] + xv.y * w[d + 1] + xv.z * w[d + 2] +
                       xv.w * w[d + 3];
            }
            feat[(Ok + j) * 100 + lane] = fmaxf(acc, 0.f);
        }
    }
}

// ---- neigh-phase (LDS children at Ok1 + j*S): mean . w + bias -> cols 50..99
template <int S>
DEVFN void level_neigh(float* __restrict__ feat, float (*snb)[104], int Ok,
                       int Ok1, int R, const float* __restrict__ w, float bias,
                       int wid, int lane) {
    for (int j = wid; j < R; j += 4) {
        if (lane < 50) {
            float a0 = 0.f, a1 = 0.f;
#pragma unroll
            for (int s = 0; s < S; ++s) {
                float2 c = *(const float2*)&feat[(Ok1 + j * S + s) * 100 + 2 * lane];
                a0 += c.x; a1 += c.y;
            }
            const float inv = 1.f / (float)S;
            *(float2*)&snb[wid][2 * lane] = make_float2(a0 * inv, a1 * inv);
            __threadfence_block();  // wave-sync LDS write->cross-lane read
            float acc = bias;
#pragma unroll
            for (int d = 0; d < 100; d += 4) {
                float4 nv = *(const float4*)&snb[wid][d];
                acc += nv.x * w[d] + nv.y * w[d + 1] + nv.z * w[d + 2] +
                       nv.w * w[d + 3];
            }
            feat[(Ok + j) * 100 + 50 + lane] = fmaxf(acc, 0.f);
        }
    }
}

// ---- pass-0 level-3 neigh-phase: children gathered from the embedding table.
// Software-pipelined: row j's 9 child rows were prefetched during row j-4's
// dot; row j+4's gathers are issued before row j's dot. n3 indices come via
// wave-uniform scalar loads (no LDS staging).
template <typename T>
DEVFN void level3_neigh_gather(float* __restrict__ feat, float (*snb)[104],
                               const T* __restrict__ embg,
                               const int* __restrict__ n3b,
                               const float* __restrict__ w, float bias,
                               int wid, int lane) {
    if (lane >= 50) return;  // no barriers inside; inactive lanes can leave

    float2 c[9];
    {
        const int j0 = __builtin_amdgcn_readfirstlane(wid);
#pragma unroll
        for (int s = 0; s < 9; ++s) {
            const int idx = n3b[j0 * 9 + s];
            c[s] = ld2(embg + (size_t)idx * 100 + 2 * lane);
        }
    }

    for (int j = wid; j < 105; j += 4) {
        float a0 = 0.f, a1 = 0.f;
#pragma unroll
        for (int s = 0; s < 9; ++s) { a0 += c[s].x; a1 += c[s].y; }
        *(float2*)&snb[wid][2 * lane] =
            make_float2(a0 * (1.f / 9.f), a1 * (1.f / 9.f));
        __threadfence_block();  // snb write -> cross-lane read

        const int jn = j + 4;
        if (jn < 105) {
            const int ju = __builtin_amdgcn_readfirstlane(jn);
#pragma unroll
            for (int s = 0; s < 9; ++s) {
                const int idx = n3b[ju * 9 + s];
                c[s] = ld2(embg + (size_t)idx * 100 + 2 * lane);
            }
        }

        float acc = bias;
#pragma unroll
        for (int d = 0; d < 100; d += 4) {
            float4 nv = *(const float4*)&snb[wid][d];
            acc += nv.x * w[d] + nv.y * w[d + 1] + nv.z * w[d + 2] +
                   nv.w * w[d + 3];
        }
        feat[(19 + j) * 100 + 50 + lane] = fmaxf(acc, 0.f);
    }
}

// ---------------------------------------------------------------------------
template <typename T>
__global__ __launch_bounds__(256, 3) void sage_fused(
    const int* __restrict__ flag, int want, const int* __restrict__ nodeids,
    const int* __restrict__ n0, const int* __restrict__ n1,
    const int* __restrict__ n2, const int* __restrict__ n3,
    const T* __restrict__ emb, const T* __restrict__ Wself,
    const T* __restrict__ bself, const T* __restrict__ Wneigh,
    const T* __restrict__ bneigh, const T* __restrict__ Wfc,
    const T* __restrict__ bfc, float* __restrict__ spec) {
    if (flag[0] != want) return;
    const int b = blockIdx.x, g = blockIdx.y;
    const int tid = threadIdx.x, wid = tid >> 6, lane = tid & 63;

    __shared__ __align__(16) float feat[12400];     // 124 rows x 100
    __shared__ __align__(16) float u_snbred[416];   // snb[4][104] | s_red[256]
    __shared__ __align__(16) int   u_idsxn[124];    // s_ids[124]  | s_xn[104]

    float (*snb)[104] = (float(*)[104])u_snbred;
    float* s_red = u_snbred;           // epilogue only (snb dead)
    int*   s_ids = u_idsxn;            // prefill only
    float* s_xn  = (float*)u_idsxn;    // epilogue only (ids dead)

    const T* embg = emb + (size_t)g * 10000000;            // (G,N,D) table
    const int* n3b = n3 + g * 483840 + b * 945;            // this tree's lvl-4 ids

    // ---- index prefill: levels 0..3 x-ids are contiguous per tree
    if (tid == 0)       s_ids[0]   = nodeids[b];
    else if (tid < 4)   s_ids[tid] = n0[g * 1536  + b * 3   + (tid - 1)];
    else if (tid < 19)  s_ids[tid] = n1[g * 7680  + b * 15  + (tid - 4)];
    else if (tid < 124) s_ids[tid] = n2[g * 53760 + b * 105 + (tid - 19)];
    __syncthreads();

    // ---- feature prefill: 124 rows x 50 float2, spread over all 256 threads
    for (int e = tid; e < 6200; e += 256) {
        const int row = e / 50, col = e - row * 50;
        *(float2*)&feat[row * 100 + 2 * col] =
            ld2(embg + (size_t)s_ids[row] * 100 + 2 * col);
    }
    __syncthreads();

    float w[100];
    auto LOADW = [&](const T* Wb) {
        if (lane < 50) {
#pragma unroll
            for (int d = 0; d < 100; ++d) w[d] = ld1(Wb + d * 50 + lane);
            // pin: prevents remat into the inner dot (R3 evidence) while the
            // 100-wide footprint stays under the 168-VGPR 3-block cap.
#pragma unroll
            for (int d = 0; d < 100; ++d) asm volatile("" : "+v"(w[d]));
        }
    };

    // ---- 4 triangular passes; per level: self-phase then neigh-phase,
    //      sharing w[] (loaded Ws then Wn). Barrier only between levels.
    for (int l = 0; l < 4; ++l) {
        const T* Wsb = Wself  + (size_t)(g * 4 + l) * 5000;
        const T* Wnb = Wneigh + (size_t)(g * 4 + l) * 5000;
        float bs = 0.f, bn = 0.f;
        if (lane < 50) {
            bs = ld1(bself  + (g * 4 + l) * 50 + lane);
            bn = ld1(bneigh + (g * 4 + l) * 50 + lane);
        }

        LOADW(Wsb); level_self(feat, 0, 1, w, bs, wid, lane);
        LOADW(Wnb); level_neigh<3>(feat, snb, 0, 1, 1, w, bn, wid, lane);
        __syncthreads();
        if (l <= 2) {
            LOADW(Wsb); level_self(feat, 1, 3, w, bs, wid, lane);
            LOADW(Wnb); level_neigh<5>(feat, snb, 1, 4, 3, w, bn, wid, lane);
            __syncthreads();
        }
        if (l <= 1) {
            LOADW(Wsb); level_self(feat, 4, 15, w, bs, wid, lane);
            LOADW(Wnb); level_neigh<7>(feat, snb, 4, 19, 15, w, bn, wid, lane);
            __syncthreads();
        }
        if (l == 0) {
            LOADW(Wsb); level_self(feat, 19, 105, w, bs, wid, lane);
            LOADW(Wnb);
            level3_neigh_gather(feat, snb, embg, n3b, w, bn, wid, lane);
            __syncthreads();
        }
    }

    // ---- epilogue: l2norm(feat[0]) @ Wfc[g] + bfc[g] -> spec[b][g][:]
    const float v = (tid < 100) ? feat[tid] : 0.f;
    s_red[tid] = v * v;
    __syncthreads();
    for (int s = 128; s > 0; s >>= 1) {
        if (tid < s) s_red[tid] += s_red[tid + s];
        __syncthreads();
    }
    const float inv = 1.f / fmaxf(sqrtf(s_red[0]), 1e-12f);
    __syncthreads();                  // s_red read done before s_xn aliasing
    if (tid < 100) s_xn[tid] = v * inv;
    __syncthreads();
    if (tid < 100) {
        const T* Wfb = Wfc + (size_t)g * 10000;
        float acc = ld1(bfc + g * 100 + tid);
#pragma unroll 4
        for (int d = 0; d < 100; ++d) acc += s_xn[d] * ld1(Wfb + d * 100 + tid);
        spec[((size_t)b * 3 + g) * 100 + tid] = acc;
    }
}

// ---------------------------------------------------------------------------
// Per-sample: pre-LN(q) attention over G=3, edge-type select, reflect matmul,
// add base embedding, l2-normalize.  Output dtype follows input dtype:
// OUT_BF16 ? bf16 : fp32.  One block per sample.  (Unchanged this round.)
// ---------------------------------------------------------------------------
template <typename T, bool OUT_BF16>
__global__ __launch_bounds__(256) void attn_out_kernel(
    const int* __restrict__ flag, int want, const float* __restrict__ spec,
    const int* __restrict__ nodeids, const int* __restrict__ edgetypes,
    const T* __restrict__ lng, const T* __restrict__ lnb,
    const T* __restrict__ Wq, const T* __restrict__ Wk,
    const T* __restrict__ Wv, const T* __restrict__ Wo,
    const T* __restrict__ refl, const T* __restrict__ base,
    void* __restrict__ out_raw) {
    if (flag[0] != want) return;
    const int b = blockIdx.x;
    const int t = threadIdx.x;

    __shared__ float s_spec[300];
    __shared__ float s_qn[100], s_Q[100];
    __shared__ float s_K[300], s_V[300];
    __shared__ float s_ctx[100], s_o[100];
    __shared__ float s_r[200];
    __shared__ float s_red[256];

    auto block_reduce = [&](float val) -> float {
        s_red[t] = val;
        __syncthreads();
        for (int s = 128; s > 0; s >>= 1) {
            if (t < s) s_red[t] += s_red[t + s];
            __syncthreads();
        }
        float r = s_red[0];
        __syncthreads();
        return r;
    };

    for (int u = t; u < 300; u += 256) s_spec[u] = spec[(size_t)b * 300 + u];
    const int e = edgetypes[b];
    __syncthreads();

    // layer-norm on the selected row only (only Q row e is ever used)
    const float v = (t < 100) ? s_spec[e * 100 + t] : 0.f;
    const float mu = block_reduce(v) * 0.01f;
    const float dv = (t < 100) ? (v - mu) : 0.f;
    const float var = block_reduce(dv * dv) * 0.01f;
    if (t < 100)
        s_qn[t] = dv * rsqrtf(var + 1e-6f) * ld1(lng + t) + ld1(lnb + t);
    __syncthreads();

    if (t < 100) {
        float acc = 0.f;
        for (int d = 0; d < 100; ++d) acc += s_qn[d] * ld1(Wq + d * 100 + t);
        s_Q[t] = acc;
        for (int h = 0; h < 3; ++h) {
            float aK = 0.f, aV = 0.f;
            for (int d = 0; d < 100; ++d) {
                const float sd = s_spec[h * 100 + d];
                aK += sd * ld1(Wk + d * 100 + t);
                aV += sd * ld1(Wv + d * 100 + t);
            }
            s_K[h * 100 + t] = aK;
            s_V[h * 100 + t] = aV;
        }
    }
    __syncthreads();

    float sc[3];
    for (int h = 0; h < 3; ++h) {
        const float p = (t < 100) ? s_Q[t] * s_K[h * 100 + t] : 0.f;
        sc[h] = block_reduce(p) * 0.1f;  // 1/sqrt(100)
    }
    const float m = fmaxf(sc[0], fmaxf(sc[1], sc[2]));
    const float e0 = expf(sc[0] - m), e1 = expf(sc[1] - m), e2 = expf(sc[2] - m);
    const float esum = e0 + e1 + e2;
    const float w0 = e0 / esum, w1 = e1 / esum, w2 = e2 / esum;

    if (t < 100)
        s_ctx[t] = w0 * s_V[t] + w1 * s_V[100 + t] + w2 * s_V[200 + t];
    __syncthreads();
    if (t < 100) {
        float acc = s_spec[e * 100 + t];  // residual
        for (int d = 0; d < 100; ++d) acc += s_ctx[d] * ld1(Wo + d * 100 + t);
        s_o[t] = acc;
    }
    __syncthreads();

    const int nid = nodeids[b];
    float sq = 0.f;
    if (t < 200) {
        float acc = ld1(base + (size_t)nid * 200 + t);
        for (int d = 0; d < 100; ++d)
            acc += s_o[d] * ld1(refl + (size_t)(e * 100 + d) * 200 + t);
        s_r[t] = acc;
        sq = acc * acc;
    }
    const float ss = block_reduce(sq);
    const float inv = 1.f / fmaxf(sqrtf(ss), 1e-12f);
    if (t < 200) {
        const float r = s_r[t] * inv;
        if constexpr (OUT_BF16)
            ((__hip_bfloat16*)out_raw)[(size_t)b * 200 + t] = __float2bfloat16(r);
        else
            ((float*)out_raw)[(size_t)b * 200 + t] = r;
    }
}

// ---------------------------------------------------------------------------
extern "C" void kernel_launch(void* const* d_in, const int* in_sizes, int n_in,
                              void* d_out, int out_size, void* d_ws,
                              size_t ws_size, hipStream_t stream) {
    (void)in_sizes; (void)n_in; (void)out_size; (void)ws_size;
    const int* nodeids   = (const int*)d_in[0];
    const int* edgetypes = (const int*)d_in[1];
    const int* n0 = (const int*)d_in[2];
    const int* n1 = (const int*)d_in[3];
    const int* n2 = (const int*)d_in[4];
    const int* n3 = (const int*)d_in[5];

    int* flag   = (int*)d_ws;
    float* SPEC = (float*)((char*)d_ws + 256);  // 512*3*100 f32

    detect_dtype<<<1, 256, 0, stream>>>((const unsigned short*)d_in[7], flag);

    // bf16 variant (flag==0)
    sage_fused<unsigned short><<<dim3(512, 3), 256, 0, stream>>>(
        flag, 0, nodeids, n0, n1, n2, n3, (const unsigned short*)d_in[7],
        (const unsigned short*)d_in[8], (const unsigned short*)d_in[9],
        (const unsigned short*)d_in[10], (const unsigned short*)d_in[11],
        (const unsigned short*)d_in[12], (const unsigned short*)d_in[13], SPEC);
    // fp32 variant (flag==1)
    sage_fused<float><<<dim3(512, 3), 256, 0, stream>>>(
        flag, 1, nodeids, n0, n1, n2, n3, (const float*)d_in[7],
        (const float*)d_in[8], (const float*)d_in[9], (const float*)d_in[10],
        (const float*)d_in[11], (const float*)d_in[12], (const float*)d_in[13],
        SPEC);

    attn_out_kernel<unsigned short, true><<<dim3(512), 256, 0, stream>>>(
        flag, 0, SPEC, nodeids, edgetypes, (const unsigned short*)d_in[14],
        (const unsigned short*)d_in[15], (const unsigned short*)d_in[16],
        (const unsigned short*)d_in[17], (const unsigned short*)d_in[18],
        (const unsigned short*)d_in[19], (const unsigned short*)d_in[20],
        (const unsigned short*)d_in[6], d_out);
    attn_out_kernel<float, false><<<dim3(512), 256, 0, stream>>>(
        flag, 1, SPEC, nodeids, edgetypes, (const float*)d_in[14],
        (const float*)d_in[15], (const float*)d_in[16], (const float*)d_in[17],
        (const float*)d_in[18], (const float*)d_in[19], (const float*)d_in[20],
        (const float*)d_in[6], d_out);
}